// Round 8
// baseline (119.604 us; speedup 1.0000x reference)
//
#include <hip/hip_runtime.h>
#include <math.h>

#define NPG 128      // nodes per graph
#define HID 64
#define ICH 151
#define EPG 2048     // edges per graph
#define TPB 512      // 8 waves
#define EPT (EPG / TPB)
#define QR  32       // x rows per GEMM quarter
#define XSS 156      // xs_q row stride, f32 (624B: 16B-aligned, bank period 8)
#define HTS 136      // ht row stride, bf16 (272B: 16B-aligned)
#define ASS 132      // As row stride, f32 (528B: 16B-aligned)
#define HT_BYTES 17408
#define STG_CHUNKS ((QR * XSS) / 64)   // 78 wave-chunks per quarter

typedef __attribute__((ext_vector_type(8))) short  short8;   // bf16x8 frag
typedef __attribute__((ext_vector_type(4))) float  floatx4;  // f32x4 acc

typedef const __attribute__((address_space(1))) void GV;     // global
typedef __attribute__((address_space(3))) void LV;           // LDS

static __device__ __forceinline__ unsigned short f2bf(float v) {
    unsigned u = __builtin_bit_cast(unsigned, v);
    return (unsigned short)((u + 0x7fffu + ((u >> 16) & 1u)) >> 16);
}
static __device__ __forceinline__ short8 pack2(floatx4 a, floatx4 b) {
    short8 r;
    r[0] = (short)f2bf(a[0]); r[1] = (short)f2bf(a[1]);
    r[2] = (short)f2bf(a[2]); r[3] = (short)f2bf(a[3]);
    r[4] = (short)f2bf(b[0]); r[5] = (short)f2bf(b[1]);
    r[6] = (short)f2bf(b[2]); r[7] = (short)f2bf(b[3]);
    return r;
}
// async global->LDS dword: LDS dest = wave-uniform base + lane*4,
// global src per-lane (gather). Drained by the vmcnt(0) in __syncthreads().
static __device__ __forceinline__ void ld_lds4(const float* src, float* lds_base) {
    __builtin_amdgcn_global_load_lds((GV*)src, (LV*)lds_base, 4, 0, 0);
}

__global__ __launch_bounds__(TPB, 6) void gcn_fused(
    const float* __restrict__ x,       // [N,151]
    const int*   __restrict__ erow,    // [E]
    const int*   __restrict__ ecol,    // [E]
    const float* __restrict__ ew,      // [E]
    const float* __restrict__ W1,      // [151,64] row-major
    const float* __restrict__ b1,      // [64]
    const float* __restrict__ Wlin,    // [8192]
    const float* __restrict__ blin,    // [1]
    float* __restrict__ out)           // [B]
{
    // Phase-aliased LDS (51200 B -> 3 blocks/CU):
    //   ht   = smem[0 .. 17408)       64x136 bf16 h^T (GEMM out, agg B-frags)
    //   xs_q = smem[17408 .. 37376)   32x156 f32 x quarter (GEMM staging)
    //   As   = smem[17408 .. 51200)   64x132 f32 half-adjacency (agg)
    __shared__ __align__(16) char smem[HT_BYTES + 64 * ASS * 4];
    __shared__ float deg[NPG];
    __shared__ float dinv[NPG];
    __shared__ float red[TPB / 64];

    short* ht = (short*)smem;
    float* xs = (float*)(smem + HT_BYTES);
    float* As = (float*)(smem + HT_BYTES);

    const int t    = threadIdx.x;
    const int g    = blockIdx.x;
    const int lane = t & 63;
    const int wv   = t >> 6;
    const int c16  = lane & 15;
    const int kq   = (lane >> 4) * 8;

    if (t < NPG) deg[t] = 1.0f;                       // self-loop weight

    // ---- edges: one coalesced scan into regs ----
    int   er_[EPT];
    int   ec_[EPT];
    float nw_[EPT];
    const int ebase = g * EPG;
    #pragma unroll
    for (int it = 0; it < EPT; ++it) {
        int e = ebase + t + it * TPB;
        er_[it] = erow[e] & (NPG - 1);
        ec_[it] = ecol[e] & (NPG - 1);
        nw_[it] = ew[e];
    }

    // ---- W1 B-fragments: direct global->reg (L1/L2-hot, loaded once) ----
    short8 bf[5];
    {
        const int ch = (wv & 3) * 16 + c16;
        #pragma unroll
        for (int s = 0; s < 5; ++s) {
            short8 v;
            #pragma unroll
            for (int j = 0; j < 8; ++j) {
                int k = s * 32 + kq + j;
                v[j] = (short)f2bf((k < ICH) ? W1[k * HID + ch] : 0.0f);
            }
            bf[s] = v;
        }
    }

    const float* xg = x + (size_t)g * (NPG * ICH);
    // ---- issue DMA stage of quarter 0 ----
    for (int i = wv; i < STG_CHUNKS; i += 8) {
        int p = i * 64 + lane;
        unsigned r = (unsigned)p / 156u;
        unsigned c = (unsigned)p - 156u * r;
        ld_lds4(xg + r * ICH + (c < (unsigned)ICH ? c : 0u), xs + i * 64);
    }

    // ---- GEMM in 4 row-quarters: h = bf16(x) @ bf16(W1) -> ht ----
    const int mq  = wv >> 2;                          // m-tile within quarter
    const int chO = (wv & 3) * 16 + c16;              // output channel
    for (int q = 0; q < 4; ++q) {
        __syncthreads();                              // stage q landed (vmcnt drain)
        short8 af[5];
        {
            const float* xrow = xs + (mq * 16 + c16) * XSS;
            #pragma unroll
            for (int s = 0; s < 4; ++s) {             // k <= 127, all valid
                floatx4 a0 = *(const floatx4*)(xrow + s * 32 + kq);
                floatx4 a1 = *(const floatx4*)(xrow + s * 32 + kq + 4);
                af[s] = pack2(a0, a1);
            }
            if (kq < 16) {                            // k = 128..143
                floatx4 a0 = *(const floatx4*)(xrow + 128 + kq);
                floatx4 a1 = *(const floatx4*)(xrow + 132 + kq);
                af[4] = pack2(a0, a1);
            } else if (kq == 16) {                    // k = 144..150 + pad
                floatx4 a0 = *(const floatx4*)(xrow + 144);
                floatx4 a1 = {xrow[148], xrow[149], xrow[150], 0.0f};
                af[4] = pack2(a0, a1);
            } else {                                  // kq == 24: all pad
                af[4] = (short8){0, 0, 0, 0, 0, 0, 0, 0};
            }
        }
        __syncthreads();                              // xs reads done -> reusable
        if (q < 3) {                                  // issue next quarter's DMA
            const float* xq = xg + (q + 1) * (QR * ICH);
            for (int i = wv; i < STG_CHUNKS; i += 8) {
                int p = i * 64 + lane;
                unsigned r = (unsigned)p / 156u;
                unsigned c = (unsigned)p - 156u * r;
                ld_lds4(xq + r * ICH + (c < (unsigned)ICH ? c : 0u), xs + i * 64);
            }
        }
        if (q == 0) {                                 // degree atomics, overlapped
            #pragma unroll
            for (int it = 0; it < EPT; ++it)
                atomicAdd(&deg[ec_[it]], nw_[it]);
        }
        floatx4 acc = {0.0f, 0.0f, 0.0f, 0.0f};
        #pragma unroll
        for (int s = 0; s < 5; ++s)
            acc = __builtin_amdgcn_mfma_f32_16x16x32_bf16(af[s], bf[s], acc, 0, 0, 0);
        // D: row = (lane>>4)*4 + r (node), col = chO -> ht[ch][node]
        int node0 = q * QR + mq * 16 + (lane >> 4) * 4;
        *(int2*)&ht[chO * HTS + node0] = make_int2(
            (int)((unsigned)f2bf(acc[0]) | ((unsigned)f2bf(acc[1]) << 16)),
            (int)((unsigned)f2bf(acc[2]) | ((unsigned)f2bf(acc[3]) << 16)));
    }
    __syncthreads();                                  // ht + deg complete

    if (t < NPG) dinv[t] = rsqrtf(deg[t]);            // deg >= 1 always
    __syncthreads();
    #pragma unroll
    for (int it = 0; it < EPT; ++it)                  // edge norms, once
        nw_[it] = dinv[er_[it]] * nw_[it] * dinv[ec_[it]];

    // ---- aggregation in 2 dst-halves: dense As (64x128) + MFMA ----
    float partial = 0.0f;
    const int mrow = (wv >> 1) * 16 + c16;            // dst row within half
    for (int half = 0; half < 2; ++half) {
        for (int p = t; p < 64 * ASS / 4; p += TPB)   // zero half-A
            ((floatx4*)As)[p] = (floatx4){0.0f, 0.0f, 0.0f, 0.0f};
        __syncthreads();

        #pragma unroll
        for (int it = 0; it < EPT; ++it) {
            int cl = ec_[it];
            if ((cl >> 6) == half)
                atomicAdd(&As[(cl & 63) * ASS + er_[it]], nw_[it]);
        }
        if (t < 64) {                                 // diagonal self-loop
            int i = half * 64 + t;
            atomicAdd(&As[t * ASS + i], dinv[i] * dinv[i]);
        }
        __syncthreads();

        short8 afr[4];
        #pragma unroll
        for (int ks = 0; ks < 4; ++ks) {
            const float* ap = &As[mrow * ASS + ks * 32 + kq];
            afr[ks] = pack2(*(const floatx4*)ap, *(const floatx4*)(ap + 4));
        }
        #pragma unroll
        for (int nn = 0; nn < 2; ++nn) {
            int nt2 = (wv & 1) * 2 + nn;
            floatx4 acc = {0.0f, 0.0f, 0.0f, 0.0f};
            #pragma unroll
            for (int ks = 0; ks < 4; ++ks) {
                short8 b = *(const short8*)&ht[(nt2 * 16 + c16) * HTS + ks * 32 + kq];
                acc = __builtin_amdgcn_mfma_f32_16x16x32_bf16(afr[ks], b, acc, 0, 0, 0);
            }
            int col = nt2 * 16 + c16;
            float b1v = b1[col];
            int node0 = half * 64 + (wv >> 1) * 16 + (lane >> 4) * 4;
            #pragma unroll
            for (int r = 0; r < 4; ++r) {
                float v = fmaxf(acc[r] + b1v, 0.0f);
                partial += v * Wlin[(node0 + r) * HID + col];
            }
        }
        __syncthreads();                              // As reads done before re-zero
    }

    // ---- block reduction + sigmoid ----
    #pragma unroll
    for (int o = 32; o > 0; o >>= 1)
        partial += __shfl_down(partial, o, 64);
    if (lane == 0) red[wv] = partial;
    __syncthreads();
    if (t == 0) {
        float tot = blin[0];
        #pragma unroll
        for (int i = 0; i < TPB / 64; ++i) tot += red[i];
        out[g] = 1.0f / (1.0f + expf(-tot));
    }
}

extern "C" void kernel_launch(void* const* d_in, const int* in_sizes, int n_in,
                              void* d_out, int out_size, void* d_ws, size_t ws_size,
                              hipStream_t stream) {
    const float* x    = (const float*)d_in[0];
    const int*   ei   = (const int*)d_in[1];
    const float* ew   = (const float*)d_in[2];
    const float* W1   = (const float*)d_in[4];
    const float* b1   = (const float*)d_in[5];
    const float* Wlin = (const float*)d_in[6];
    const float* blin = (const float*)d_in[7];
    float* out = (float*)d_out;

    const int E = in_sizes[1] / 2;     // edge_index is [2, E]
    const int B = out_size;            // 2048 graphs

    gcn_fused<<<B, TPB, 0, stream>>>(x, ei, ei + E, ew, W1, b1, Wlin, blin, out);
}

// Round 10
// 91.415 us; speedup vs baseline: 1.3084x; 1.3084x over previous
//
#include <hip/hip_runtime.h>
#include <math.h>

#define NPG 128      // nodes per graph
#define HID 64
#define ICH 151
#define EPG 2048     // edges per graph
#define TPB 512      // 8 waves
#define EPT (EPG / TPB)
#define BTS 168      // W1^T row stride, bf16 (336B: 16B-aligned, 2-way banks)
#define HTS 136      // h^T row stride, bf16 (272B: 16B-aligned, 2-way banks)
#define ASS 132      // As row stride, f32 (528B: 16B-aligned, 2-way banks)
#define BT_OFF 17408 // byte offset of bt/As region (= ht bytes)

typedef __attribute__((ext_vector_type(8))) short  short8;   // bf16x8 frag
typedef __attribute__((ext_vector_type(4))) float  floatx4;  // f32x4 acc

// software fp32->bf16 RNE (proven in R4/R6/R8 passes; cvt_pk asm NaN'd in R7/R9)
static __device__ __forceinline__ unsigned short f2bf(float v) {
    unsigned u = __builtin_bit_cast(unsigned, v);
    return (unsigned short)((u + 0x7fffu + ((u >> 16) & 1u)) >> 16);
}
static __device__ __forceinline__ unsigned packbf(float a, float b) {
    return (unsigned)f2bf(a) | ((unsigned)f2bf(b) << 16);
}
static __device__ __forceinline__ short8 pack8(const float* v) {
    union { unsigned u[4]; short8 s; } r;
    r.u[0] = packbf(v[0], v[1]);
    r.u[1] = packbf(v[2], v[3]);
    r.u[2] = packbf(v[4], v[5]);
    r.u[3] = packbf(v[6], v[7]);
    return r.s;
}

__global__ __launch_bounds__(TPB, 8) void gcn_fused(
    const float* __restrict__ x,       // [N,151]
    const int*   __restrict__ erow,    // [E]
    const int*   __restrict__ ecol,    // [E]
    const float* __restrict__ ew,      // [E]
    const float* __restrict__ W1,      // [151,64] row-major
    const float* __restrict__ b1,      // [64]
    const float* __restrict__ Wlin,    // [8192]
    const float* __restrict__ blin,    // [1]
    float* __restrict__ out)           // [B]
{
    // Phase-aliased LDS (38912 B + ~1KB statics -> 4 blocks/CU):
    //   ht = smem[0 .. 17408)        64x136 bf16 h^T (GEMM out, agg B-frags)
    //   bt = smem[17408 .. 38912)    64x168 bf16 W1^T (GEMM only)
    //   As = smem[17408 .. 34304)    32x132 f32 quarter-adjacency (agg)
    __shared__ __align__(16) char smem[38912];
    __shared__ float deg[NPG];
    __shared__ float dinv[NPG];
    __shared__ float red[TPB / 64];

    short* ht = (short*)smem;
    short* bt = (short*)(smem + BT_OFF);
    float* As = (float*)(smem + BT_OFF);

    const int t    = threadIdx.x;
    const int g    = blockIdx.x;
    const int lane = t & 63;
    const int wv   = t >> 6;
    const int c16  = lane & 15;
    const int kq   = (lane >> 4) * 8;

    if (t < NPG) deg[t] = 1.0f;                       // self-loop weight

    // ---- edges: one coalesced scan into regs ----
    int   er_[EPT];
    int   ec_[EPT];
    float nw_[EPT];
    const int ebase = g * EPG;
    #pragma unroll
    for (int it = 0; it < EPT; ++it) {
        int e = ebase + t + it * TPB;
        er_[it] = erow[e] & (NPG - 1);
        ec_[it] = ecol[e] & (NPG - 1);
        nw_[it] = ew[e];
    }

    // ---- x A-fragments: direct guarded scalar loads (proven in R4) ----
    short8 af[5];
    {
        const float* xr = x + (size_t)g * (NPG * ICH) + (wv * 16 + c16) * ICH;
        #pragma unroll
        for (int s = 0; s < 5; ++s) {
            float v[8];
            #pragma unroll
            for (int j = 0; j < 8; ++j) {
                int k = s * 32 + kq + j;
                v[j] = (k < ICH) ? xr[k] : 0.0f;
            }
            af[s] = pack8(v);
        }
    }

    // ---- stage W1^T bf16 into bt (k-pad zeroed) ----
    {
        const int c = t & 63, k0 = (t >> 6) * 2;
        for (int k = k0; k < BTS; k += 16) {
            float w0 = (k     < ICH) ? W1[k * HID + c]       : 0.0f;
            float w1 = (k + 1 < ICH) ? W1[(k + 1) * HID + c] : 0.0f;
            *(unsigned*)&bt[c * BTS + k] = packbf(w0, w1);
        }
    }
    __syncthreads();                                   // bar1: deg-init + bt ready

    // ---- degree atomics (edges in regs) ----
    #pragma unroll
    for (int it = 0; it < EPT; ++it)
        atomicAdd(&deg[ec_[it]], nw_[it]);

    // ---- GEMM h = x @ W1 -> ht (bf16, [col][row]) ----
    #pragma unroll
    for (int n = 0; n < 4; ++n) {
        floatx4 acc = {0.0f, 0.0f, 0.0f, 0.0f};
        #pragma unroll
        for (int s = 0; s < 5; ++s) {
            short8 b = *(const short8*)&bt[(n * 16 + c16) * BTS + s * 32 + kq];
            acc = __builtin_amdgcn_mfma_f32_16x16x32_bf16(af[s], b, acc, 0, 0, 0);
        }
        // D: row = (lane>>4)*4 + r, col = n*16 + c16  -> ht[col][row]
        int col = n * 16 + c16;
        int row = wv * 16 + (lane >> 4) * 4;
        *(int2*)&ht[col * HTS + row] =
            make_int2((int)packbf(acc[0], acc[1]), (int)packbf(acc[2], acc[3]));
    }
    __syncthreads();                                   // bar2: deg + ht done, bt dead

    if (t < NPG) dinv[t] = rsqrtf(deg[t]);             // deg >= 1 always
    __syncthreads();                                   // bar3: dinv ready

    #pragma unroll
    for (int it = 0; it < EPT; ++it)                   // precompute edge norms once
        nw_[it] = dinv[er_[it]] * nw_[it] * dinv[ec_[it]];

    // ---- aggregation in 4 dst-quarters: build As (32x128) then MFMA ----
    float partial = 0.0f;
    const int mt   = wv >> 2;                          // 0..1: m-tile in quarter
    const int ntb  = wv & 3;                           // 0..3: n-tile (channels)
    const int col  = ntb * 16 + c16;
    const int arow = mt * 16 + c16;                    // A-frag row within quarter
    const float b1v = b1[col];

    for (int q = 0; q < 4; ++q) {
        for (int p = t; p < 32 * ASS / 4; p += TPB)    // zero quarter-A
            ((floatx4*)As)[p] = (floatx4){0.0f, 0.0f, 0.0f, 0.0f};
        __syncthreads();                               // barA: zero done

        #pragma unroll
        for (int it = 0; it < EPT; ++it) {
            int cl = ec_[it];
            if ((cl >> 5) == q)
                atomicAdd(&As[(cl & 31) * ASS + er_[it]], nw_[it]);
        }
        if (t < 32) {                                  // diagonal self-loop
            int i = q * 32 + t;
            atomicAdd(&As[t * ASS + i], dinv[i] * dinv[i]);
        }
        __syncthreads();                               // barB: As built

        short8 afr[4];                                 // A frags -> bf16
        #pragma unroll
        for (int ks = 0; ks < 4; ++ks) {
            const float* ap = &As[arow * ASS + ks * 32 + kq];
            floatx4 a0 = *(const floatx4*)ap;
            floatx4 a1 = *(const floatx4*)(ap + 4);
            float v[8] = {a0[0], a0[1], a0[2], a0[3], a1[0], a1[1], a1[2], a1[3]};
            afr[ks] = pack8(v);
        }
        __syncthreads();                               // barC: As reads done ->
                                                       // MFMA overlaps next zero
        floatx4 acc = {0.0f, 0.0f, 0.0f, 0.0f};
        #pragma unroll
        for (int ks = 0; ks < 4; ++ks) {
            short8 b = *(const short8*)&ht[col * HTS + ks * 32 + kq];
            acc = __builtin_amdgcn_mfma_f32_16x16x32_bf16(afr[ks], b, acc, 0, 0, 0);
        }
        int node0 = q * 32 + mt * 16 + (lane >> 4) * 4;
        #pragma unroll
        for (int r = 0; r < 4; ++r) {
            float v = fmaxf(acc[r] + b1v, 0.0f);
            partial += v * Wlin[(node0 + r) * HID + col];
        }
    }

    // ---- block reduction + sigmoid ----
    #pragma unroll
    for (int o = 32; o > 0; o >>= 1)
        partial += __shfl_down(partial, o, 64);
    if (lane == 0) red[wv] = partial;
    __syncthreads();
    if (t == 0) {
        float tot = blin[0];
        #pragma unroll
        for (int i = 0; i < TPB / 64; ++i) tot += red[i];
        out[g] = 1.0f / (1.0f + expf(-tot));
    }
}

extern "C" void kernel_launch(void* const* d_in, const int* in_sizes, int n_in,
                              void* d_out, int out_size, void* d_ws, size_t ws_size,
                              hipStream_t stream) {
    const float* x    = (const float*)d_in[0];
    const int*   ei   = (const int*)d_in[1];
    const float* ew   = (const float*)d_in[2];
    const float* W1   = (const float*)d_in[4];
    const float* b1   = (const float*)d_in[5];
    const float* Wlin = (const float*)d_in[6];
    const float* blin = (const float*)d_in[7];
    float* out = (float*)d_out;

    const int E = in_sizes[1] / 2;     // edge_index is [2, E]
    const int B = out_size;            // 2048 graphs

    gcn_fused<<<B, TPB, 0, stream>>>(x, ei, ei + E, ew, W1, b1, Wlin, blin, out);
}

// Round 11
// 90.930 us; speedup vs baseline: 1.3153x; 1.0053x over previous
//
#include <hip/hip_runtime.h>
#include <math.h>

#define NPG 128      // nodes per graph
#define HID 64
#define ICH 151
#define EPG 2048     // edges per graph
#define TPB 512      // 8 waves
#define EPT (EPG / TPB)
#define BTS 168      // W1^T row stride, bf16 (336B: 16B-aligned, 2-way banks)
#define HTS 136      // h^T row stride, bf16 (272B: 16B-aligned, 2-way banks)
#define ASS 132      // As row stride, f32 (528B: 16B-aligned, 2-way banks)
#define BT_OFF 17408 // byte offset of bt/As region (= ht bytes)

typedef __attribute__((ext_vector_type(8))) short  short8;   // bf16x8 frag
typedef __attribute__((ext_vector_type(4))) float  floatx4;  // f32x4 acc

// software fp32->bf16 RNE (proven R4/R6/R8/R10; cvt_pk asm NaN'd in R7/R9)
static __device__ __forceinline__ unsigned short f2bf(float v) {
    unsigned u = __builtin_bit_cast(unsigned, v);
    return (unsigned short)((u + 0x7fffu + ((u >> 16) & 1u)) >> 16);
}
static __device__ __forceinline__ unsigned packbf(float a, float b) {
    return (unsigned)f2bf(a) | ((unsigned)f2bf(b) << 16);
}
static __device__ __forceinline__ short8 pack8(const float* v) {
    union { unsigned u[4]; short8 s; } r;
    r.u[0] = packbf(v[0], v[1]);
    r.u[1] = packbf(v[2], v[3]);
    r.u[2] = packbf(v[4], v[5]);
    r.u[3] = packbf(v[6], v[7]);
    return r.s;
}

// NOTE: launch_bounds (512,6): the (512,8) bound in R10 made the allocator
// squeeze to 32 VGPR and spill ~20MB to scratch (WRITE_SIZE evidence).
// (512,6) empirically yields VGPR=40, no spill; 40<=64 still permits
// 8 waves/SIMD at runtime, and LDS 38.9KB gives 4 blocks/CU.
__global__ __launch_bounds__(TPB, 6) void gcn_fused(
    const float* __restrict__ x,       // [N,151]
    const int*   __restrict__ erow,    // [E]
    const int*   __restrict__ ecol,    // [E]
    const float* __restrict__ ew,      // [E]
    const float* __restrict__ W1,      // [151,64] row-major
    const float* __restrict__ b1,      // [64]
    const float* __restrict__ Wlin,    // [8192]
    const float* __restrict__ blin,    // [1]
    float* __restrict__ out)           // [B]
{
    // Phase-aliased LDS (38912 B + ~1KB statics -> 4 blocks/CU):
    //   ht = smem[0 .. 17408)        64x136 bf16 h^T (GEMM out, agg B-frags)
    //   bt = smem[17408 .. 38912)    64x168 bf16 W1^T (GEMM only)
    //   As = smem[17408 .. 34304)    32x132 f32 quarter-adjacency (agg)
    __shared__ __align__(16) char smem[38912];
    __shared__ float deg[NPG];
    __shared__ float dinv[NPG];
    __shared__ float red[TPB / 64];

    short* ht = (short*)smem;
    short* bt = (short*)(smem + BT_OFF);
    float* As = (float*)(smem + BT_OFF);

    const int t    = threadIdx.x;
    const int g    = blockIdx.x;
    const int lane = t & 63;
    const int wv   = t >> 6;
    const int c16  = lane & 15;
    const int kq   = (lane >> 4) * 8;

    if (t < NPG) deg[t] = 1.0f;                       // self-loop weight

    // ---- edges: one coalesced scan, packed into regs ----
    int   ep_[EPT];                                   // (cl<<7) | rl
    float nw_[EPT];
    const int ebase = g * EPG;
    #pragma unroll
    for (int it = 0; it < EPT; ++it) {
        int e = ebase + t + it * TPB;
        int rl = erow[e] & (NPG - 1);
        int cl = ecol[e] & (NPG - 1);
        ep_[it] = (cl << 7) | rl;
        nw_[it] = ew[e];
    }

    // ---- x A-fragments: direct guarded scalar loads (proven in R4) ----
    short8 af[5];
    {
        const float* xr = x + (size_t)g * (NPG * ICH) + (wv * 16 + c16) * ICH;
        #pragma unroll
        for (int s = 0; s < 5; ++s) {
            float v[8];
            #pragma unroll
            for (int j = 0; j < 8; ++j) {
                int k = s * 32 + kq + j;
                v[j] = (k < ICH) ? xr[k] : 0.0f;
            }
            af[s] = pack8(v);
        }
    }

    // ---- stage W1^T bf16 into bt (k-pad zeroed) ----
    {
        const int c = t & 63, k0 = (t >> 6) * 2;
        for (int k = k0; k < BTS; k += 16) {
            float w0 = (k     < ICH) ? W1[k * HID + c]       : 0.0f;
            float w1 = (k + 1 < ICH) ? W1[(k + 1) * HID + c] : 0.0f;
            *(unsigned*)&bt[c * BTS + k] = packbf(w0, w1);
        }
    }
    __syncthreads();                                   // bar1: deg-init + bt ready

    // ---- degree atomics (edges in regs) ----
    #pragma unroll
    for (int it = 0; it < EPT; ++it)
        atomicAdd(&deg[ep_[it] >> 7], nw_[it]);

    // ---- GEMM h = x @ W1 -> ht (bf16, [col][row]) ----
    #pragma unroll
    for (int n = 0; n < 4; ++n) {
        floatx4 acc = {0.0f, 0.0f, 0.0f, 0.0f};
        #pragma unroll
        for (int s = 0; s < 5; ++s) {
            short8 b = *(const short8*)&bt[(n * 16 + c16) * BTS + s * 32 + kq];
            acc = __builtin_amdgcn_mfma_f32_16x16x32_bf16(af[s], b, acc, 0, 0, 0);
        }
        // D: row = (lane>>4)*4 + r, col = n*16 + c16  -> ht[col][row]
        int col = n * 16 + c16;
        int row = wv * 16 + (lane >> 4) * 4;
        *(int2*)&ht[col * HTS + row] =
            make_int2((int)packbf(acc[0], acc[1]), (int)packbf(acc[2], acc[3]));
    }
    __syncthreads();                                   // bar2: deg + ht done, bt dead

    if (t < NPG) dinv[t] = rsqrtf(deg[t]);             // deg >= 1 always
    __syncthreads();                                   // bar3: dinv ready

    #pragma unroll
    for (int it = 0; it < EPT; ++it) {                 // precompute edge norms once
        int rl = ep_[it] & (NPG - 1), cl = ep_[it] >> 7;
        nw_[it] = dinv[rl] * nw_[it] * dinv[cl];
    }

    // ---- aggregation in 4 dst-quarters: build As (32x128) then MFMA ----
    float partial = 0.0f;
    const int mt   = wv >> 2;                          // 0..1: m-tile in quarter
    const int ntb  = wv & 3;                           // 0..3: n-tile (channels)
    const int col  = ntb * 16 + c16;
    const int arow = mt * 16 + c16;                    // A-frag row within quarter
    const float b1v = b1[col];

    for (int q = 0; q < 4; ++q) {
        for (int p = t; p < 32 * ASS / 4; p += TPB)    // zero quarter-A
            ((floatx4*)As)[p] = (floatx4){0.0f, 0.0f, 0.0f, 0.0f};
        __syncthreads();                               // barA: zero done

        #pragma unroll
        for (int it = 0; it < EPT; ++it) {
            int cl = ep_[it] >> 7;
            if ((cl >> 5) == q)
                atomicAdd(&As[(cl & 31) * ASS + (ep_[it] & (NPG - 1))], nw_[it]);
        }
        if (t < 32) {                                  // diagonal self-loop
            int i = q * 32 + t;
            atomicAdd(&As[t * ASS + i], dinv[i] * dinv[i]);
        }
        __syncthreads();                               // barB: As built

        short8 afr[4];                                 // A frags -> bf16
        #pragma unroll
        for (int ks = 0; ks < 4; ++ks) {
            const float* ap = &As[arow * ASS + ks * 32 + kq];
            floatx4 a0 = *(const floatx4*)ap;
            floatx4 a1 = *(const floatx4*)(ap + 4);
            float v[8] = {a0[0], a0[1], a0[2], a0[3], a1[0], a1[1], a1[2], a1[3]};
            afr[ks] = pack8(v);
        }
        __syncthreads();                               // barC: As reads done ->
                                                       // MFMA overlaps next zero
        floatx4 acc = {0.0f, 0.0f, 0.0f, 0.0f};
        #pragma unroll
        for (int ks = 0; ks < 4; ++ks) {
            short8 b = *(const short8*)&ht[col * HTS + ks * 32 + kq];
            acc = __builtin_amdgcn_mfma_f32_16x16x32_bf16(afr[ks], b, acc, 0, 0, 0);
        }
        int node0 = q * 32 + mt * 16 + (lane >> 4) * 4;
        #pragma unroll
        for (int r = 0; r < 4; ++r) {
            float v = fmaxf(acc[r] + b1v, 0.0f);
            partial += v * Wlin[(node0 + r) * HID + col];
        }
    }

    // ---- block reduction + sigmoid ----
    #pragma unroll
    for (int o = 32; o > 0; o >>= 1)
        partial += __shfl_down(partial, o, 64);
    if (lane == 0) red[wv] = partial;
    __syncthreads();
    if (t == 0) {
        float tot = blin[0];
        #pragma unroll
        for (int i = 0; i < TPB / 64; ++i) tot += red[i];
        out[g] = 1.0f / (1.0f + expf(-tot));
    }
}

extern "C" void kernel_launch(void* const* d_in, const int* in_sizes, int n_in,
                              void* d_out, int out_size, void* d_ws, size_t ws_size,
                              hipStream_t stream) {
    const float* x    = (const float*)d_in[0];
    const int*   ei   = (const int*)d_in[1];
    const float* ew   = (const float*)d_in[2];
    const float* W1   = (const float*)d_in[4];
    const float* b1   = (const float*)d_in[5];
    const float* Wlin = (const float*)d_in[6];
    const float* blin = (const float*)d_in[7];
    float* out = (float*)d_out;

    const int E = in_sizes[1] / 2;     // edge_index is [2, E]
    const int B = out_size;            // 2048 graphs

    gcn_fused<<<B, TPB, 0, stream>>>(x, ei, ei + E, ew, W1, b1, Wlin, blin, out);
}

// Round 12
// 83.664 us; speedup vs baseline: 1.4296x; 1.0869x over previous
//
#include <hip/hip_runtime.h>
#include <math.h>

#define NPG 128      // nodes per graph
#define HID 64
#define ICH 151
#define EPG 2048     // edges per graph
#define TPB 512      // 8 waves
#define EPT (EPG / TPB)
#define KP  160      // padded K (5 MFMA k-steps of 32)
#define HTS 136      // h^T row stride, bf16 (272B: 16B-aligned, 2-way banks)
#define ASS 132      // As row stride, f32 (528B: 16B-aligned, 2-way banks)
#define AS_OFF 17408 // byte offset of As region (= ht bytes)

typedef __attribute__((ext_vector_type(8))) short  short8;   // bf16x8 frag
typedef __attribute__((ext_vector_type(4))) float  floatx4;  // f32x4 acc

// software fp32->bf16 RNE (proven R4/R6/R8/R10/R11; cvt_pk asm NaN'd R7/R9)
static __device__ __forceinline__ unsigned short f2bf(float v) {
    unsigned u = __builtin_bit_cast(unsigned, v);
    return (unsigned short)((u + 0x7fffu + ((u >> 16) & 1u)) >> 16);
}
static __device__ __forceinline__ unsigned packbf(float a, float b) {
    return (unsigned)f2bf(a) | ((unsigned)f2bf(b) << 16);
}
static __device__ __forceinline__ short8 pack8(const float* v) {
    union { unsigned u[4]; short8 s; } r;
    r.u[0] = packbf(v[0], v[1]);
    r.u[1] = packbf(v[2], v[3]);
    r.u[2] = packbf(v[4], v[5]);
    r.u[3] = packbf(v[6], v[7]);
    return r.s;
}

// ---- prep: W1 [151][64] f32 -> W1T [64][160] bf16 (k-pad zeroed) ----
__global__ __launch_bounds__(512) void gcn_prep(const float* __restrict__ W1,
                                                short* __restrict__ W1T) {
    int i = threadIdx.x + blockIdx.x * 512;          // 10240 elements exactly
    if (i < HID * KP) {
        int ch = i / KP, k = i - ch * KP;
        W1T[i] = (short)f2bf((k < ICH) ? W1[k * HID + ch] : 0.0f);
    }
}

__global__ __launch_bounds__(TPB, 6) void gcn_fused(
    const float* __restrict__ x,       // [N,151]
    const int*   __restrict__ erow,    // [E]
    const int*   __restrict__ ecol,    // [E]
    const float* __restrict__ ew,      // [E]
    const short* __restrict__ W1T,     // [64][160] bf16 (prepped)
    const float* __restrict__ b1,      // [64]
    const float* __restrict__ Wlin,    // [8192]
    const float* __restrict__ blin,    // [1]
    float* __restrict__ out)           // [B]
{
    // LDS (51200 B + ~1KB statics -> 3 blocks/CU), no aliasing:
    //   ht = smem[0 .. 17408)        64x136 bf16 h^T (GEMM out, agg B-frags)
    //   As = smem[17408 .. 51200)    64x132 f32 half-adjacency
    __shared__ __align__(16) char smem[AS_OFF + 64 * ASS * 4];
    __shared__ float deg[NPG];
    __shared__ float dinv[NPG];
    __shared__ float red[TPB / 64];

    short* ht = (short*)smem;
    float* As = (float*)(smem + AS_OFF);

    const int t    = threadIdx.x;
    const int g    = blockIdx.x;
    const int lane = t & 63;
    const int wv   = t >> 6;
    const int c16  = lane & 15;
    const int kq   = (lane >> 4) * 8;

    if (t < NPG) deg[t] = 1.0f;                       // self-loop weight

    // ---- edges: one coalesced scan, packed into regs ----
    int   ep_[EPT];                                   // (cl<<7) | rl
    float nw_[EPT];
    const int ebase = g * EPG;
    #pragma unroll
    for (int it = 0; it < EPT; ++it) {
        int e = ebase + t + it * TPB;
        int rl = erow[e] & (NPG - 1);
        int cl = ecol[e] & (NPG - 1);
        ep_[it] = (cl << 7) | rl;
        nw_[it] = ew[e];
    }

    // ---- x A-fragments: direct guarded scalar loads (proven R4/R11) ----
    short8 af[5];
    {
        const float* xr = x + (size_t)g * (NPG * ICH) + (wv * 16 + c16) * ICH;
        #pragma unroll
        for (int s = 0; s < 5; ++s) {
            float v[8];
            #pragma unroll
            for (int j = 0; j < 8; ++j) {
                int k = s * 32 + kq + j;
                v[j] = (k < ICH) ? xr[k] : 0.0f;
            }
            af[s] = pack8(v);
        }
    }
    __syncthreads();                                   // bar1: deg-init visible

    // ---- degree atomics (edges in regs) ----
    #pragma unroll
    for (int it = 0; it < EPT; ++it)
        atomicAdd(&deg[ep_[it] >> 7], nw_[it]);

    // ---- GEMM h = x @ W1 -> ht; B-frags = 16B vector loads from W1T ----
    #pragma unroll
    for (int n = 0; n < 4; ++n) {
        floatx4 acc = {0.0f, 0.0f, 0.0f, 0.0f};
        #pragma unroll
        for (int s = 0; s < 5; ++s) {
            short8 b = *(const short8*)&W1T[(n * 16 + c16) * KP + s * 32 + kq];
            acc = __builtin_amdgcn_mfma_f32_16x16x32_bf16(af[s], b, acc, 0, 0, 0);
        }
        // D: row = (lane>>4)*4 + r, col = n*16 + c16  -> ht[col][row]
        int col = n * 16 + c16;
        int row = wv * 16 + (lane >> 4) * 4;
        *(int2*)&ht[col * HTS + row] =
            make_int2((int)packbf(acc[0], acc[1]), (int)packbf(acc[2], acc[3]));
    }
    __syncthreads();                                   // bar2: deg + ht done

    if (t < NPG) dinv[t] = rsqrtf(deg[t]);             // deg >= 1 always
    __syncthreads();                                   // bar3: dinv ready

    #pragma unroll
    for (int it = 0; it < EPT; ++it) {                 // precompute edge norms once
        int rl = ep_[it] & (NPG - 1), cl = ep_[it] >> 7;
        nw_[it] = dinv[rl] * nw_[it] * dinv[cl];
    }

    // ---- aggregation in 2 dst-halves: build As (64x128) then MFMA ----
    float partial = 0.0f;
    const int mrow = (wv >> 1) * 16 + c16;             // dst row within half

    for (int half = 0; half < 2; ++half) {
        for (int p = t; p < 64 * ASS / 4; p += TPB)    // zero half-A
            ((floatx4*)As)[p] = (floatx4){0.0f, 0.0f, 0.0f, 0.0f};
        __syncthreads();                               // barA: zero done

        #pragma unroll
        for (int it = 0; it < EPT; ++it) {
            int cl = ep_[it] >> 7;
            if ((cl >> 6) == half)
                atomicAdd(&As[(cl & 63) * ASS + (ep_[it] & (NPG - 1))], nw_[it]);
        }
        if (t < 64) {                                  // diagonal self-loop
            int i = half * 64 + t;
            atomicAdd(&As[t * ASS + i], dinv[i] * dinv[i]);
        }
        __syncthreads();                               // barB: As built

        short8 afr[4];                                 // A frags -> bf16
        #pragma unroll
        for (int ks = 0; ks < 4; ++ks) {
            const float* ap = &As[mrow * ASS + ks * 32 + kq];
            floatx4 a0 = *(const floatx4*)ap;
            floatx4 a1 = *(const floatx4*)(ap + 4);
            float v[8] = {a0[0], a0[1], a0[2], a0[3], a1[0], a1[1], a1[2], a1[3]};
            afr[ks] = pack8(v);
        }
        #pragma unroll
        for (int nn = 0; nn < 2; ++nn) {
            int nt2 = (wv & 1) * 2 + nn;
            floatx4 acc = {0.0f, 0.0f, 0.0f, 0.0f};
            #pragma unroll
            for (int ks = 0; ks < 4; ++ks) {
                short8 b = *(const short8*)&ht[(nt2 * 16 + c16) * HTS + ks * 32 + kq];
                acc = __builtin_amdgcn_mfma_f32_16x16x32_bf16(afr[ks], b, acc, 0, 0, 0);
            }
            int col = nt2 * 16 + c16;
            float b1v = b1[col];
            int node0 = half * 64 + (wv >> 1) * 16 + (lane >> 4) * 4;
            #pragma unroll
            for (int r = 0; r < 4; ++r) {
                float v = fmaxf(acc[r] + b1v, 0.0f);
                partial += v * Wlin[(node0 + r) * HID + col];
            }
        }
        __syncthreads();                               // barC: As reads done
    }

    // ---- block reduction + sigmoid ----
    #pragma unroll
    for (int o = 32; o > 0; o >>= 1)
        partial += __shfl_down(partial, o, 64);
    if (lane == 0) red[wv] = partial;
    __syncthreads();
    if (t == 0) {
        float tot = blin[0];
        #pragma unroll
        for (int i = 0; i < TPB / 64; ++i) tot += red[i];
        out[g] = 1.0f / (1.0f + expf(-tot));
    }
}

extern "C" void kernel_launch(void* const* d_in, const int* in_sizes, int n_in,
                              void* d_out, int out_size, void* d_ws, size_t ws_size,
                              hipStream_t stream) {
    const float* x    = (const float*)d_in[0];
    const int*   ei   = (const int*)d_in[1];
    const float* ew   = (const float*)d_in[2];
    const float* W1   = (const float*)d_in[4];
    const float* b1   = (const float*)d_in[5];
    const float* Wlin = (const float*)d_in[6];
    const float* blin = (const float*)d_in[7];
    float* out = (float*)d_out;

    const int E = in_sizes[1] / 2;     // edge_index is [2, E]
    const int B = out_size;            // 2048 graphs

    short* W1T = (short*)d_ws;         // [64][160] bf16 = 20480 B

    gcn_prep<<<(HID * KP + 511) / 512, 512, 0, stream>>>(W1, W1T);
    gcn_fused<<<B, TPB, 0, stream>>>(x, ei, ei + E, ew, W1T, b1, Wlin, blin, out);
}